// Round 1
// baseline (669.731 us; speedup 1.0000x reference)
//
#include <hip/hip_runtime.h>

#define CCH 16

__global__ void zero_f(float* __restrict__ p, int n) {
    int i = blockIdx.x * blockDim.x + threadIdx.x;
    if (i < n) p[i] = 0.0f;
}

__global__ void zero_f4(float4* __restrict__ p, int n4) {
    int i = blockIdx.x * blockDim.x + threadIdx.x;
    if (i < n4) p[i] = make_float4(0.f, 0.f, 0.f, 0.f);
}

// One thread per (point, channel). Lanes 0..15 of a point hit 16 consecutive
// output floats (one 64B line); input load is fully coalesced 4B/lane.
__global__ void scatter_add_kernel(const float* __restrict__ in,
                                   const int* __restrict__ seg,
                                   float* __restrict__ sums,
                                   float* __restrict__ counts,
                                   int N) {
    int tid = blockIdx.x * blockDim.x + threadIdx.x;   // 16*N threads
    int p = tid >> 4;
    int c = tid & 15;
    if (p >= N) return;
    int s = seg[p];                 // 16 lanes read same dword -> one line
    float v = in[tid];
    // unsafeAtomicAdd -> global_atomic_add_f32 (HW fadd, no CAS loop)
    unsafeAtomicAdd(&sums[s * CCH + c], v);
    if (c == 0) unsafeAtomicAdd(&counts[s], 1.0f);
}

__global__ void finalize_kernel(float4* __restrict__ out,
                                const float* __restrict__ counts,
                                int n4 /* = M*4 */) {
    int i = blockIdx.x * blockDim.x + threadIdx.x;
    if (i >= n4) return;
    int m = i >> 2;                 // 4 float4 per segment row
    float inv = 1.0f / fmaxf(counts[m], 1.0f);
    float4 v = out[i];
    v.x *= inv; v.y *= inv; v.z *= inv; v.w *= inv;
    out[i] = v;
}

extern "C" void kernel_launch(void* const* d_in, const int* in_sizes, int n_in,
                              void* d_out, int out_size, void* d_ws, size_t ws_size,
                              hipStream_t stream) {
    const float* in  = (const float*)d_in[0];
    const int*   seg = (const int*)d_in[1];
    float* out    = (float*)d_out;
    float* counts = (float*)d_ws;

    const int N = in_sizes[0] / CCH;   // 4,000,000
    const int M = out_size / CCH;      // 500,000

    // Zero sum accumulator (in d_out) and counts (in d_ws) — harness poisons
    // both with 0xAA before every timed call.
    {
        int n4 = out_size / 4;         // out_size = M*16, divisible by 4
        zero_f4<<<(n4 + 255) / 256, 256, 0, stream>>>((float4*)d_out, n4);
        zero_f<<<(M + 255) / 256, 256, 0, stream>>>(counts, M);
    }

    // Scatter-add sums and counts.
    {
        long long total = (long long)N * CCH;
        int grid = (int)((total + 255) / 256);
        scatter_add_kernel<<<grid, 256, 0, stream>>>(in, seg, out, counts, N);
    }

    // Divide by clamped counts, in place.
    {
        int n4 = out_size / 4;
        finalize_kernel<<<(n4 + 255) / 256, 256, 0, stream>>>((float4*)d_out, counts, n4);
    }
}